// Round 12
// baseline (166.746 us; speedup 1.0000x reference)
//
#include <hip/hip_runtime.h>
#include <math.h>

// FundusQuantumLayer: DIAGNOSTIC ROUND.
// R7-R11 measured: {s_load,LDS}x{SPT1,2}x{scalar,pk}x{split,fused} all 20-25us
// vs 5.2us HBM floor. Every visible variant was stall-bound (VALUBusy ~32%).
// fq_main never surfaces in rocprof top-5 (hidden under 40us poison fills).
// This kernel repeats R7's exact per-sample body REP=16x with opaque asm
// barriers (no CSE/hoist; "+s" on table ptr forces per-iteration s_loads).
// Output identical & deterministic. Purpose: surface fq_main WITH counters
// (VGPR/Occupancy/VALUBusy/hbm_bytes) and split per-sample vs memory cost
// by the scaling factor.

typedef float f4 __attribute__((ext_vector_type(4)));
typedef const f4 __attribute__((address_space(4)))* c4ptr;  // constant AS -> s_load

#define REP 16

__global__ void fq_setup(const float* __restrict__ w, float4* __restrict__ Ct) {
    __shared__ float2 sU[16][16];      // U[row][col] (re,im) of shared block
    __shared__ float  sReM[4][16][16]; // Re(U^dag Z_q U)
    const int tid = threadIdx.x;

    {   // ---- Stage A: thread (r,c) holds U[r][c].
        const int r = tid & 15, c = tid >> 4;
        float ar = (r == c) ? 1.f : 0.f, ai = 0.f;
#pragma unroll
        for (int l = 0; l < 3; ++l) {
#pragma unroll
            for (int q = 0; q < 4; ++q) {
                const int m = 1 << (3 - q);          // qubit 0 = MSB
                {   // RY
                    float th = w[(l*4 + q)*2 + 0];
                    float cg = __cosf(0.5f*th), sg = __sinf(0.5f*th);
                    float obr = __shfl_xor(ar, m, 64);
                    float obi = __shfl_xor(ai, m, 64);
                    float t2 = (r & m) ? sg : -sg;
                    ar = cg*ar + t2*obr;
                    ai = cg*ai + t2*obi;
                }
                {   // RZ
                    float ph = w[(l*4 + q)*2 + 1];
                    float cp = __cosf(0.5f*ph), sp = __sinf(0.5f*ph);
                    float t2 = (r & m) ? sp : -sp;
                    float nr = cp*ar - t2*ai;
                    float ni = cp*ai + t2*ar;
                    ar = nr; ai = ni;
                }
            }
#pragma unroll
            for (int e = 0; e < 4; ++e) {            // CNOT ring
                const int mc = 1 << (3 - e);
                const int mt = 1 << (3 - ((e + 1) & 3));
                float obr = __shfl_xor(ar, mt, 64);
                float obi = __shfl_xor(ai, mt, 64);
                if (r & mc) { ar = obr; ai = obi; }
            }
        }
        sU[r][c] = make_float2(ar, ai);
    }
    __syncthreads();

    {   // ---- Stage B
        const int i = tid >> 4, j = tid & 15;
        float s0 = 0.f, s1 = 0.f, s2 = 0.f, s3 = 0.f;
#pragma unroll
        for (int k = 0; k < 16; ++k) {
            float2 uik = sU[k][i], ujk = sU[k][j];
            float pr = uik.x*ujk.x + uik.y*ujk.y;
            s0 += (k & 8) ? -pr : pr;
            s1 += (k & 4) ? -pr : pr;
            s2 += (k & 2) ? -pr : pr;
            s3 += (k & 1) ? -pr : pr;
        }
        sReM[0][i][j] = s0; sReM[1][i][j] = s1;
        sReM[2][i][j] = s2; sReM[3][i][j] = s3;
    }
    __syncthreads();

    // ---- Stage C
    for (int idx = tid; idx < 324; idx += 256) {
        int q = idx / 81, k81 = idx % 81;
        int p0 = k81/27, p1 = (k81/9)%3, p2 = (k81/3)%3, p3 = k81%3;
        int xm = 0, zm = 0;
        if (p0 == 1) zm |= 8; else if (p0 == 2) xm |= 8;
        if (p1 == 1) zm |= 4; else if (p1 == 2) xm |= 4;
        if (p2 == 1) zm |= 2; else if (p2 == 2) xm |= 2;
        if (p3 == 1) zm |= 1; else if (p3 == 2) xm |= 1;
        float sum = 0.f;
#pragma unroll
        for (int j = 0; j < 16; ++j) {
            float sgn = (__popc(j & zm) & 1) ? -1.f : 1.f;
            sum += sgn * sReM[q][j ^ xm][j];
        }
        ((float*)Ct)[k81*4 + q] = sum * 0.0625f;
    }
}

__global__ __launch_bounds__(256) void fq_main(const float4* __restrict__ x,
                                               const float* __restrict__ Ct,
                                               float4* __restrict__ out) {
    const int i = blockIdx.x * 256 + threadIdx.x;
    float4 xv = x[i];
    float4 o = make_float4(0.f, 0.f, 0.f, 0.f);

#pragma unroll 1
    for (int k = 0; k < REP; ++k) {
        // Opaque copies: prevent CSE/hoisting across iterations (rule #17).
        float xx = xv.x, xy = xv.y, xz = xv.z, xw = xv.w;
        asm volatile("" : "+v"(xx), "+v"(xy), "+v"(xz), "+v"(xw));
        unsigned long long Cp = (unsigned long long)Ct;
        asm volatile("" : "+s"(Cp));           // force per-iteration s_loads
        c4ptr C = (c4ptr)Cp;

        // ---- R7's exact per-sample body ----
        float c0 = __cosf(xx), s0 = __sinf(xx);
        float c1 = __cosf(xy), s1 = __sinf(xy);
        float c2 = __cosf(xz), s2 = __sinf(xz);
        float c3 = __cosf(xw), s3 = __sinf(xw);

        float f0[3] = {1.f, c0, s0}, f1[3] = {1.f, c1, s1};
        float f2v[3] = {1.f, c2, s2}, f3[3] = {1.f, c3, s3};
        float g01[9], g23[9];
#pragma unroll
        for (int a = 0; a < 3; ++a)
#pragma unroll
            for (int b = 0; b < 3; ++b) {
                g01[a*3+b] = f0[a] * f1[b];
                g23[a*3+b] = f2v[a] * f3[b];
            }

        float a0 = 0.f, a1 = 0.f, a2 = 0.f, a3 = 0.f;
#pragma unroll
        for (int a = 0; a < 9; ++a) {
            float t0 = 0.f, t1 = 0.f, t2 = 0.f, t3 = 0.f;
#pragma unroll
            for (int b = 0; b < 9; ++b) {
                f4 c = C[a*9 + b];             // s_load_dwordx4 (uniform addr)
                float g = g23[b];
                t0 = fmaf(c[0], g, t0);
                t1 = fmaf(c[1], g, t1);
                t2 = fmaf(c[2], g, t2);
                t3 = fmaf(c[3], g, t3);
            }
            float g = g01[a];
            a0 = fmaf(t0, g, a0);
            a1 = fmaf(t1, g, a1);
            a2 = fmaf(t2, g, a2);
            a3 = fmaf(t3, g, a3);
        }
        // ---- end body ----

        o = make_float4(a0, a1, a2, a3);
        asm volatile("" : "+v"(o.x), "+v"(o.y), "+v"(o.z), "+v"(o.w));
    }

    out[i] = o;
}

extern "C" void kernel_launch(void* const* d_in, const int* in_sizes, int n_in,
                              void* d_out, int out_size, void* d_ws, size_t ws_size,
                              hipStream_t stream) {
    const float* x = (const float*)d_in[0];     // [B,4] f32
    const float* w = (const float*)d_in[1];     // [3,4,2] f32
    float4* Ct = (float4*)d_ws;                 // 81 float4 scratch

    fq_setup<<<1, 256, 0, stream>>>(w, Ct);

    const int B = in_sizes[0] / 4;              // 1048576
    fq_main<<<B / 256, 256, 0, stream>>>((const float4*)x, (const float*)Ct,
                                         (float4*)d_out);
}

// Round 13
// 22.408 us; speedup vs baseline: 7.4415x; 7.4415x over previous
//
#include <hip/hip_runtime.h>
#include <math.h>

// FundusQuantumLayer: 4-qubit, 3-layer variational circuit, batch 2^20.
// ev[q] = sum_{P in {I,Z,X}^4} C[q][P] * prod_r w_{P_r}(x_r), w = (1,cos x,sin x).
// Kernel 1 builds C (4x81) once; kernel 2 streams samples.
//
// Measured history:
//  R7: AS4 s_load table, SPT=1, scalar fma -> 20.6us (best)
//  R8-R11: SPT/LDS/fused variants -> 20-25us (all neutral)
//  R12 DIAGNOSTIC (REP=16 of R7 body): 180us, VALUBusy 98.4%, VGPR 16
//    => body is VALU-ISSUE-BOUND at ~830 instrs/sample (2x the ideal ~400;
//       compiler rematerializes at tiny VGPR budget). SMEM fully hidden.
//    => R9's builtin "packed" never lowered to v_pk_fma_f32 (was neutral).
// This round: hand-forced v_pk_fma_f32 via inline asm. Coefficient pairs
// come straight from s_load_dwordx4 SGPR pairs (1 scalar operand/instr is
// legal); {g,g} VGPR pairs built once per sample. 180 pk-ops replace 360
// scalar fmas; body ~230 instrs.

typedef float f4 __attribute__((ext_vector_type(4)));
typedef float f2 __attribute__((ext_vector_type(2)));
typedef const f4 __attribute__((address_space(4)))* c4ptr;  // constant AS -> s_load

__global__ void fq_setup(const float* __restrict__ w, float4* __restrict__ Ct) {
    __shared__ float2 sU[16][16];      // U[row][col] (re,im) of shared block
    __shared__ float  sReM[4][16][16]; // Re(U^dag Z_q U)
    const int tid = threadIdx.x;

    {   // ---- Stage A: thread (r,c) holds U[r][c].
        const int r = tid & 15, c = tid >> 4;
        float ar = (r == c) ? 1.f : 0.f, ai = 0.f;
#pragma unroll
        for (int l = 0; l < 3; ++l) {
#pragma unroll
            for (int q = 0; q < 4; ++q) {
                const int m = 1 << (3 - q);          // qubit 0 = MSB
                {   // RY
                    float th = w[(l*4 + q)*2 + 0];
                    float cg = __cosf(0.5f*th), sg = __sinf(0.5f*th);
                    float obr = __shfl_xor(ar, m, 64);
                    float obi = __shfl_xor(ai, m, 64);
                    float t2 = (r & m) ? sg : -sg;
                    ar = cg*ar + t2*obr;
                    ai = cg*ai + t2*obi;
                }
                {   // RZ
                    float ph = w[(l*4 + q)*2 + 1];
                    float cp = __cosf(0.5f*ph), sp = __sinf(0.5f*ph);
                    float t2 = (r & m) ? sp : -sp;
                    float nr = cp*ar - t2*ai;
                    float ni = cp*ai + t2*ar;
                    ar = nr; ai = ni;
                }
            }
#pragma unroll
            for (int e = 0; e < 4; ++e) {            // CNOT ring
                const int mc = 1 << (3 - e);
                const int mt = 1 << (3 - ((e + 1) & 3));
                float obr = __shfl_xor(ar, mt, 64);
                float obi = __shfl_xor(ai, mt, 64);
                if (r & mc) { ar = obr; ai = obi; }
            }
        }
        sU[r][c] = make_float2(ar, ai);
    }
    __syncthreads();

    {   // ---- Stage B: ReM[q][i][j] = sum_k z_q(k) Re(conj(U[k][i]) U[k][j])
        const int i = tid >> 4, j = tid & 15;
        float s0 = 0.f, s1 = 0.f, s2 = 0.f, s3 = 0.f;
#pragma unroll
        for (int k = 0; k < 16; ++k) {
            float2 uik = sU[k][i], ujk = sU[k][j];
            float pr = uik.x*ujk.x + uik.y*ujk.y;
            s0 += (k & 8) ? -pr : pr;
            s1 += (k & 4) ? -pr : pr;
            s2 += (k & 2) ? -pr : pr;
            s3 += (k & 1) ? -pr : pr;
        }
        sReM[0][i][j] = s0; sReM[1][i][j] = s1;
        sReM[2][i][j] = s2; sReM[3][i][j] = s3;
    }
    __syncthreads();

    // ---- Stage C: Ct[k81].q = tr(M_q P_{k81})/16, digits: 0=I 1=Z 2=X
    for (int idx = tid; idx < 324; idx += 256) {
        int q = idx / 81, k81 = idx % 81;
        int p0 = k81/27, p1 = (k81/9)%3, p2 = (k81/3)%3, p3 = k81%3;
        int xm = 0, zm = 0;
        if (p0 == 1) zm |= 8; else if (p0 == 2) xm |= 8;
        if (p1 == 1) zm |= 4; else if (p1 == 2) xm |= 4;
        if (p2 == 1) zm |= 2; else if (p2 == 2) xm |= 2;
        if (p3 == 1) zm |= 1; else if (p3 == 2) xm |= 1;
        float sum = 0.f;
#pragma unroll
        for (int j = 0; j < 16; ++j) {
            float sgn = (__popc(j & zm) & 1) ? -1.f : 1.f;
            sum += sgn * sReM[q][j ^ xm][j];
        }
        ((float*)Ct)[k81*4 + q] = sum * 0.0625f;
    }
}

__global__ __launch_bounds__(256) void fq_main(const float4* __restrict__ x,
                                               const float* __restrict__ Ct,
                                               float4* __restrict__ out) {
    const int i = blockIdx.x * 256 + threadIdx.x;
    c4ptr C = (c4ptr)(unsigned long long)Ct;   // uniform addr -> s_load_dwordx4

    float4 xv = x[i];
    float c0, s0, c1, s1, c2, s2, c3, s3;
    __sincosf(xv.x, &s0, &c0);
    __sincosf(xv.y, &s1, &c1);
    __sincosf(xv.z, &s2, &c2);
    __sincosf(xv.w, &s3, &c3);

    float f0[3] = {1.f, c0, s0}, f1[3] = {1.f, c1, s1};
    float f2v[3] = {1.f, c2, s2}, f3[3] = {1.f, c3, s3};

    // Broadcast pairs {g,g} built once per sample (VGPR pairs for VOP3P).
    f2 gg01[9], gg23[9];
#pragma unroll
    for (int a = 0; a < 3; ++a)
#pragma unroll
        for (int b = 0; b < 3; ++b) {
            float u = f0[a] * f1[b];           // *1.0f entries fold
            float v = f2v[a] * f3[b];
            gg01[a*3+b] = (f2){u, u};
            gg23[a*3+b] = (f2){v, v};
        }

    f2 A01 = {0.f, 0.f}, A23 = {0.f, 0.f};    // (ev0,ev1), (ev2,ev3)
#pragma unroll
    for (int a = 0; a < 9; ++a) {
        f2 t01 = {0.f, 0.f}, t23 = {0.f, 0.f};
#pragma unroll
        for (int b = 0; b < 9; ++b) {
            f4 c = C[a*9 + b];                 // 4 consecutive SGPRs
            unsigned long long cu01 =
                __builtin_bit_cast(unsigned long long, (f2){c[0], c[1]});
            unsigned long long cu23 =
                __builtin_bit_cast(unsigned long long, (f2){c[2], c[3]});
            // Packed fp32 FMA, coefficient pair as the single scalar operand.
            asm("v_pk_fma_f32 %0, %2, %3, %0\n\t"
                "v_pk_fma_f32 %1, %4, %3, %1"
                : "+v"(t01), "+v"(t23)
                : "s"(cu01), "v"(gg23[b]), "s"(cu23));
        }
        asm("v_pk_fma_f32 %0, %2, %3, %0\n\t"
            "v_pk_fma_f32 %1, %4, %3, %1"
            : "+v"(A01), "+v"(A23)
            : "v"(t01), "v"(gg01[a]), "v"(t23));
    }

    out[i] = make_float4(A01.x, A01.y, A23.x, A23.y);
}

extern "C" void kernel_launch(void* const* d_in, const int* in_sizes, int n_in,
                              void* d_out, int out_size, void* d_ws, size_t ws_size,
                              hipStream_t stream) {
    const float* x = (const float*)d_in[0];     // [B,4] f32
    const float* w = (const float*)d_in[1];     // [3,4,2] f32
    float4* Ct = (float4*)d_ws;                 // 81 float4 scratch

    fq_setup<<<1, 256, 0, stream>>>(w, Ct);

    const int B = in_sizes[0] / 4;              // 1048576
    fq_main<<<B / 256, 256, 0, stream>>>((const float4*)x, (const float*)Ct,
                                         (float4*)d_out);
}

// Round 14
// 21.860 us; speedup vs baseline: 7.6280x; 1.0251x over previous
//
#include <hip/hip_runtime.h>
#include <math.h>

// FundusQuantumLayer: 4-qubit, 3-layer variational circuit, batch 2^20.
// ev[q] = sum_{P in {I,Z,X}^4} C[q][P] * prod_r w_{P_r}(x_r), w = (1,cos x,sin x).
// Kernel 1 builds C (4x81) once; kernel 2 streams samples.
//
// Measured history:
//  R7: AS4 s_load table, SPT=1, scalar fma, __cosf/__sinf -> 20.6us (best)
//  R8-R11: SPT/LDS/fused variants -> 20-25us (all neutral)
//  R12 DIAGNOSTIC: body VALU-bound, 98.4% busy, VGPR_Count=16 (!!), SGPR=48
//    => compiler's occupancy heuristic picks a tiny VGPR budget and
//       REMATERIALIZES g-products at every use: ~830 instr/sample vs ~430
//       ideal. <=64 VGPR is occupancy-free (m69) - the remat buys nothing.
//  R13: asm v_pk_fma_f32 (+__sincosf) -> 22.4us; pk semantics correct
//       (passed) but remat still ate the gain; __sincosf costs ~+3us
//       (R10/R13 vs R7/R9).
// This round: (1) opaque-pin the 18 {g,g} pairs in VGPRs (anti-remat fence),
// (2) launch_bounds(256,3) -> cap 84 (measured), live ~62, no spill,
// (3) keep asm pk-fma, (4) __cosf/__sinf.

typedef float f4 __attribute__((ext_vector_type(4)));
typedef float f2 __attribute__((ext_vector_type(2)));
typedef const f4 __attribute__((address_space(4)))* c4ptr;  // constant AS -> s_load

__global__ void fq_setup(const float* __restrict__ w, float4* __restrict__ Ct) {
    __shared__ float2 sU[16][16];      // U[row][col] (re,im) of shared block
    __shared__ float  sReM[4][16][16]; // Re(U^dag Z_q U)
    const int tid = threadIdx.x;

    {   // ---- Stage A: thread (r,c) holds U[r][c].
        const int r = tid & 15, c = tid >> 4;
        float ar = (r == c) ? 1.f : 0.f, ai = 0.f;
#pragma unroll
        for (int l = 0; l < 3; ++l) {
#pragma unroll
            for (int q = 0; q < 4; ++q) {
                const int m = 1 << (3 - q);          // qubit 0 = MSB
                {   // RY
                    float th = w[(l*4 + q)*2 + 0];
                    float cg = __cosf(0.5f*th), sg = __sinf(0.5f*th);
                    float obr = __shfl_xor(ar, m, 64);
                    float obi = __shfl_xor(ai, m, 64);
                    float t2 = (r & m) ? sg : -sg;
                    ar = cg*ar + t2*obr;
                    ai = cg*ai + t2*obi;
                }
                {   // RZ
                    float ph = w[(l*4 + q)*2 + 1];
                    float cp = __cosf(0.5f*ph), sp = __sinf(0.5f*ph);
                    float t2 = (r & m) ? sp : -sp;
                    float nr = cp*ar - t2*ai;
                    float ni = cp*ai + t2*ar;
                    ar = nr; ai = ni;
                }
            }
#pragma unroll
            for (int e = 0; e < 4; ++e) {            // CNOT ring
                const int mc = 1 << (3 - e);
                const int mt = 1 << (3 - ((e + 1) & 3));
                float obr = __shfl_xor(ar, mt, 64);
                float obi = __shfl_xor(ai, mt, 64);
                if (r & mc) { ar = obr; ai = obi; }
            }
        }
        sU[r][c] = make_float2(ar, ai);
    }
    __syncthreads();

    {   // ---- Stage B: ReM[q][i][j] = sum_k z_q(k) Re(conj(U[k][i]) U[k][j])
        const int i = tid >> 4, j = tid & 15;
        float s0 = 0.f, s1 = 0.f, s2 = 0.f, s3 = 0.f;
#pragma unroll
        for (int k = 0; k < 16; ++k) {
            float2 uik = sU[k][i], ujk = sU[k][j];
            float pr = uik.x*ujk.x + uik.y*ujk.y;
            s0 += (k & 8) ? -pr : pr;
            s1 += (k & 4) ? -pr : pr;
            s2 += (k & 2) ? -pr : pr;
            s3 += (k & 1) ? -pr : pr;
        }
        sReM[0][i][j] = s0; sReM[1][i][j] = s1;
        sReM[2][i][j] = s2; sReM[3][i][j] = s3;
    }
    __syncthreads();

    // ---- Stage C: Ct[k81].q = tr(M_q P_{k81})/16, digits: 0=I 1=Z 2=X
    for (int idx = tid; idx < 324; idx += 256) {
        int q = idx / 81, k81 = idx % 81;
        int p0 = k81/27, p1 = (k81/9)%3, p2 = (k81/3)%3, p3 = k81%3;
        int xm = 0, zm = 0;
        if (p0 == 1) zm |= 8; else if (p0 == 2) xm |= 8;
        if (p1 == 1) zm |= 4; else if (p1 == 2) xm |= 4;
        if (p2 == 1) zm |= 2; else if (p2 == 2) xm |= 2;
        if (p3 == 1) zm |= 1; else if (p3 == 2) xm |= 1;
        float sum = 0.f;
#pragma unroll
        for (int j = 0; j < 16; ++j) {
            float sgn = (__popc(j & zm) & 1) ? -1.f : 1.f;
            sum += sgn * sReM[q][j ^ xm][j];
        }
        ((float*)Ct)[k81*4 + q] = sum * 0.0625f;
    }
}

__global__ __launch_bounds__(256, 3) void fq_main(const float4* __restrict__ x,
                                                  const float* __restrict__ Ct,
                                                  float4* __restrict__ out) {
    const int i = blockIdx.x * 256 + threadIdx.x;
    c4ptr C = (c4ptr)(unsigned long long)Ct;   // uniform addr -> s_load_dwordx4

    float4 xv = x[i];
    float c0 = __cosf(xv.x), s0 = __sinf(xv.x);
    float c1 = __cosf(xv.y), s1 = __sinf(xv.y);
    float c2 = __cosf(xv.z), s2 = __sinf(xv.z);
    float c3 = __cosf(xv.w), s3 = __sinf(xv.w);

    float f0[3] = {1.f, c0, s0}, f1[3] = {1.f, c1, s1};
    float f2v[3] = {1.f, c2, s2}, f3[3] = {1.f, c3, s3};

    // Broadcast pairs {g,g}: build once, then PIN in VGPRs (anti-remat).
    f2 gg01[9], gg23[9];
#pragma unroll
    for (int a = 0; a < 3; ++a)
#pragma unroll
        for (int b = 0; b < 3; ++b) {
            float u = f0[a] * f1[b];           // *1.0f entries fold
            float v = f2v[a] * f3[b];
            gg01[a*3+b] = (f2){u, u};
            gg23[a*3+b] = (f2){v, v};
        }
    // Opaque fence: forces all 18 pairs to be materialized & kept in VGPRs.
    asm("" : "+v"(gg01[0]), "+v"(gg01[1]), "+v"(gg01[2]), "+v"(gg01[3]),
             "+v"(gg01[4]), "+v"(gg01[5]), "+v"(gg01[6]), "+v"(gg01[7]),
             "+v"(gg01[8]),
             "+v"(gg23[0]), "+v"(gg23[1]), "+v"(gg23[2]), "+v"(gg23[3]),
             "+v"(gg23[4]), "+v"(gg23[5]), "+v"(gg23[6]), "+v"(gg23[7]),
             "+v"(gg23[8]));

    f2 A01 = {0.f, 0.f}, A23 = {0.f, 0.f};    // (ev0,ev1), (ev2,ev3)
#pragma unroll
    for (int a = 0; a < 9; ++a) {
        f2 t01 = {0.f, 0.f}, t23 = {0.f, 0.f};
#pragma unroll
        for (int b = 0; b < 9; ++b) {
            f4 c = C[a*9 + b];                 // 4 consecutive SGPRs
            unsigned long long cu01 =
                __builtin_bit_cast(unsigned long long, (f2){c[0], c[1]});
            unsigned long long cu23 =
                __builtin_bit_cast(unsigned long long, (f2){c[2], c[3]});
            // Packed fp32 FMA; coefficient pair = the one scalar operand.
            asm("v_pk_fma_f32 %0, %2, %3, %0\n\t"
                "v_pk_fma_f32 %1, %4, %3, %1"
                : "+v"(t01), "+v"(t23)
                : "s"(cu01), "v"(gg23[b]), "s"(cu23));
        }
        asm("v_pk_fma_f32 %0, %2, %3, %0\n\t"
            "v_pk_fma_f32 %1, %4, %3, %1"
            : "+v"(A01), "+v"(A23)
            : "v"(t01), "v"(gg01[a]), "v"(t23));
    }

    out[i] = make_float4(A01.x, A01.y, A23.x, A23.y);
}

extern "C" void kernel_launch(void* const* d_in, const int* in_sizes, int n_in,
                              void* d_out, int out_size, void* d_ws, size_t ws_size,
                              hipStream_t stream) {
    const float* x = (const float*)d_in[0];     // [B,4] f32
    const float* w = (const float*)d_in[1];     // [3,4,2] f32
    float4* Ct = (float4*)d_ws;                 // 81 float4 scratch

    fq_setup<<<1, 256, 0, stream>>>(w, Ct);

    const int B = in_sizes[0] / 4;              // 1048576
    fq_main<<<B / 256, 256, 0, stream>>>((const float4*)x, (const float*)Ct,
                                         (float4*)d_out);
}

// Round 15
// 21.501 us; speedup vs baseline: 7.7551x; 1.0167x over previous
//
#include <hip/hip_runtime.h>
#include <math.h>

// FundusQuantumLayer: 4-qubit, 3-layer variational circuit, batch 2^20.
// ev[q] = sum_{P in {I,Z,X}^4} C[q][P] * prod_r w_{P_r}(x_r), w = (1,cos x,sin x).
// Kernel 1 builds C (4x81) once; kernel 2 streams samples.
//
// Measured history (key):
//  R7: s_load table, scalar fma -> 20.6us. R12 diag: body VALU-bound, 98.4%
//  busy, ~830 instr/sample (2x ideal; remat at VGPR=16).
//  R10/R11: LDS-broadcast table -> 23.9/25.4us (81 ds_read_b128/sample
//  serializes the per-CU LDS pipe ~11us chip-wide; LDS table is a dead end).
//  R13/R14: asm v_pk_fma_f32 with "s"((f2){c[0],c[1]}) -> +1.3us vs R7.
//    Diagnosis: vector-construction->bit_cast->"s" routes through VGPRs and
//    forces v_readfirstlane_b32 x324 to satisfy the constraint, swallowing
//    the packed-FMA saving. The pk instructions themselves are correct.
// This round: load coefficients NATIVELY as 64-bit scalars via an AS4
// unsigned-long-long pointer -> s_load_dwordx2/x4 yields i64 SGPR pairs
// directly; "s" operands consume them with ZERO repack. Rest = R14.

typedef float f4 __attribute__((ext_vector_type(4)));
typedef float f2 __attribute__((ext_vector_type(2)));
typedef const unsigned long long __attribute__((address_space(4)))* cu64ptr;

__global__ void fq_setup(const float* __restrict__ w, float4* __restrict__ Ct) {
    __shared__ float2 sU[16][16];      // U[row][col] (re,im) of shared block
    __shared__ float  sReM[4][16][16]; // Re(U^dag Z_q U)
    const int tid = threadIdx.x;

    {   // ---- Stage A: thread (r,c) holds U[r][c].
        const int r = tid & 15, c = tid >> 4;
        float ar = (r == c) ? 1.f : 0.f, ai = 0.f;
#pragma unroll
        for (int l = 0; l < 3; ++l) {
#pragma unroll
            for (int q = 0; q < 4; ++q) {
                const int m = 1 << (3 - q);          // qubit 0 = MSB
                {   // RY
                    float th = w[(l*4 + q)*2 + 0];
                    float cg = __cosf(0.5f*th), sg = __sinf(0.5f*th);
                    float obr = __shfl_xor(ar, m, 64);
                    float obi = __shfl_xor(ai, m, 64);
                    float t2 = (r & m) ? sg : -sg;
                    ar = cg*ar + t2*obr;
                    ai = cg*ai + t2*obi;
                }
                {   // RZ
                    float ph = w[(l*4 + q)*2 + 1];
                    float cp = __cosf(0.5f*ph), sp = __sinf(0.5f*ph);
                    float t2 = (r & m) ? sp : -sp;
                    float nr = cp*ar - t2*ai;
                    float ni = cp*ai + t2*ar;
                    ar = nr; ai = ni;
                }
            }
#pragma unroll
            for (int e = 0; e < 4; ++e) {            // CNOT ring
                const int mc = 1 << (3 - e);
                const int mt = 1 << (3 - ((e + 1) & 3));
                float obr = __shfl_xor(ar, mt, 64);
                float obi = __shfl_xor(ai, mt, 64);
                if (r & mc) { ar = obr; ai = obi; }
            }
        }
        sU[r][c] = make_float2(ar, ai);
    }
    __syncthreads();

    {   // ---- Stage B: ReM[q][i][j] = sum_k z_q(k) Re(conj(U[k][i]) U[k][j])
        const int i = tid >> 4, j = tid & 15;
        float s0 = 0.f, s1 = 0.f, s2 = 0.f, s3 = 0.f;
#pragma unroll
        for (int k = 0; k < 16; ++k) {
            float2 uik = sU[k][i], ujk = sU[k][j];
            float pr = uik.x*ujk.x + uik.y*ujk.y;
            s0 += (k & 8) ? -pr : pr;
            s1 += (k & 4) ? -pr : pr;
            s2 += (k & 2) ? -pr : pr;
            s3 += (k & 1) ? -pr : pr;
        }
        sReM[0][i][j] = s0; sReM[1][i][j] = s1;
        sReM[2][i][j] = s2; sReM[3][i][j] = s3;
    }
    __syncthreads();

    // ---- Stage C: Ct[k81].q = tr(M_q P_{k81})/16, digits: 0=I 1=Z 2=X
    for (int idx = tid; idx < 324; idx += 256) {
        int q = idx / 81, k81 = idx % 81;
        int p0 = k81/27, p1 = (k81/9)%3, p2 = (k81/3)%3, p3 = k81%3;
        int xm = 0, zm = 0;
        if (p0 == 1) zm |= 8; else if (p0 == 2) xm |= 8;
        if (p1 == 1) zm |= 4; else if (p1 == 2) xm |= 4;
        if (p2 == 1) zm |= 2; else if (p2 == 2) xm |= 2;
        if (p3 == 1) zm |= 1; else if (p3 == 2) xm |= 1;
        float sum = 0.f;
#pragma unroll
        for (int j = 0; j < 16; ++j) {
            float sgn = (__popc(j & zm) & 1) ? -1.f : 1.f;
            sum += sgn * sReM[q][j ^ xm][j];
        }
        ((float*)Ct)[k81*4 + q] = sum * 0.0625f;
    }
}

__global__ __launch_bounds__(256, 3) void fq_main(const float4* __restrict__ x,
                                                  const float* __restrict__ Ct,
                                                  float4* __restrict__ out) {
    const int i = blockIdx.x * 256 + threadIdx.x;
    // Coefficients as native 64-bit scalars: s_load -> even-aligned SGPR
    // pairs, consumed by v_pk_fma_f32 "s" operands with zero repack.
    cu64ptr CU = (cu64ptr)(unsigned long long)Ct;

    float4 xv = x[i];
    float c0 = __cosf(xv.x), s0 = __sinf(xv.x);
    float c1 = __cosf(xv.y), s1 = __sinf(xv.y);
    float c2 = __cosf(xv.z), s2 = __sinf(xv.z);
    float c3 = __cosf(xv.w), s3 = __sinf(xv.w);

    float f0[3] = {1.f, c0, s0}, f1[3] = {1.f, c1, s1};
    float f2v[3] = {1.f, c2, s2}, f3[3] = {1.f, c3, s3};

    // Broadcast pairs {g,g}: build once, PIN in VGPRs (anti-remat, R14).
    f2 gg01[9], gg23[9];
#pragma unroll
    for (int a = 0; a < 3; ++a)
#pragma unroll
        for (int b = 0; b < 3; ++b) {
            float u = f0[a] * f1[b];           // *1.0f entries fold
            float v = f2v[a] * f3[b];
            gg01[a*3+b] = (f2){u, u};
            gg23[a*3+b] = (f2){v, v};
        }
    asm("" : "+v"(gg01[0]), "+v"(gg01[1]), "+v"(gg01[2]), "+v"(gg01[3]),
             "+v"(gg01[4]), "+v"(gg01[5]), "+v"(gg01[6]), "+v"(gg01[7]),
             "+v"(gg01[8]),
             "+v"(gg23[0]), "+v"(gg23[1]), "+v"(gg23[2]), "+v"(gg23[3]),
             "+v"(gg23[4]), "+v"(gg23[5]), "+v"(gg23[6]), "+v"(gg23[7]),
             "+v"(gg23[8]));

    f2 A01 = {0.f, 0.f}, A23 = {0.f, 0.f};    // (ev0,ev1), (ev2,ev3)
#pragma unroll
    for (int a = 0; a < 9; ++a) {
        f2 t01 = {0.f, 0.f}, t23 = {0.f, 0.f};
#pragma unroll
        for (int b = 0; b < 9; ++b) {
            unsigned long long cu01 = CU[(a*9 + b)*2 + 0];  // (C[q0],C[q1])
            unsigned long long cu23 = CU[(a*9 + b)*2 + 1];  // (C[q2],C[q3])
            // Packed fp32 FMA; coefficient pair = the one scalar operand.
            asm("v_pk_fma_f32 %0, %2, %3, %0\n\t"
                "v_pk_fma_f32 %1, %4, %3, %1"
                : "+v"(t01), "+v"(t23)
                : "s"(cu01), "v"(gg23[b]), "s"(cu23));
        }
        asm("v_pk_fma_f32 %0, %2, %3, %0\n\t"
            "v_pk_fma_f32 %1, %4, %3, %1"
            : "+v"(A01), "+v"(A23)
            : "v"(t01), "v"(gg01[a]), "v"(t23));
    }

    out[i] = make_float4(A01.x, A01.y, A23.x, A23.y);
}

extern "C" void kernel_launch(void* const* d_in, const int* in_sizes, int n_in,
                              void* d_out, int out_size, void* d_ws, size_t ws_size,
                              hipStream_t stream) {
    const float* x = (const float*)d_in[0];     // [B,4] f32
    const float* w = (const float*)d_in[1];     // [3,4,2] f32
    float4* Ct = (float4*)d_ws;                 // 81 float4 scratch

    fq_setup<<<1, 256, 0, stream>>>(w, Ct);

    const int B = in_sizes[0] / 4;              // 1048576
    fq_main<<<B / 256, 256, 0, stream>>>((const float4*)x, (const float*)Ct,
                                         (float4*)d_out);
}

// Round 16
// 20.712 us; speedup vs baseline: 8.0508x; 1.0381x over previous
//
#include <hip/hip_runtime.h>
#include <math.h>

// FundusQuantumLayer: 4-qubit, 3-layer variational circuit, batch 2^20.
// ev[q] = sum_{P in {I,Z,X}^4} C[q][P] * prod_r w_{P_r}(x_r), w = (1,cos x,sin x).
// Kernel 1 builds C (4x81) once; kernel 2 streams samples.
//
// Measured history (key):
//  R7: AS4 s_load table, scalar fma, float ARRAYS g01[9]/g23[9] -> 20.6us
//  R12 diag: REP=16 -> 180us, VALUBusy 98.4%, VGPR_Count=16 (!), ~830
//    instr/sample. VGPR=16 cannot hold the arrays => they were NEVER
//    register-promoted: SROA runs before #pragma unroll resolves indices
//    (guide rule #20), so every g[b] access is a scratch buffer_load
//    (L2-hot, no HBM signature) + waitcnt. ~180 VMEM/sample = the 2x bloat.
//  R8-R15: SPT/LDS/pk-fma/SGPR-operand variants all 20-25us -- all kept the
//    arrays, so all inherited the scratch round-trips. Flatness explained.
// This round (rule #20's prescribed fix): ZERO arrays -- 18 named g scalars,
// fully hand-unrolled 81x(4 fma) chain via macros, every index literal.
// Coefficients via R7's proven AS4 f4 s_loads. No pk, no asm, no caps.

typedef float f4 __attribute__((ext_vector_type(4)));
typedef const f4 __attribute__((address_space(4)))* c4ptr;  // constant AS -> s_load

__global__ void fq_setup(const float* __restrict__ w, float4* __restrict__ Ct) {
    __shared__ float2 sU[16][16];      // U[row][col] (re,im) of shared block
    __shared__ float  sReM[4][16][16]; // Re(U^dag Z_q U)
    const int tid = threadIdx.x;

    {   // ---- Stage A: thread (r,c) holds U[r][c].
        const int r = tid & 15, c = tid >> 4;
        float ar = (r == c) ? 1.f : 0.f, ai = 0.f;
#pragma unroll
        for (int l = 0; l < 3; ++l) {
#pragma unroll
            for (int q = 0; q < 4; ++q) {
                const int m = 1 << (3 - q);          // qubit 0 = MSB
                {   // RY
                    float th = w[(l*4 + q)*2 + 0];
                    float cg = __cosf(0.5f*th), sg = __sinf(0.5f*th);
                    float obr = __shfl_xor(ar, m, 64);
                    float obi = __shfl_xor(ai, m, 64);
                    float t2 = (r & m) ? sg : -sg;
                    ar = cg*ar + t2*obr;
                    ai = cg*ai + t2*obi;
                }
                {   // RZ
                    float ph = w[(l*4 + q)*2 + 1];
                    float cp = __cosf(0.5f*ph), sp = __sinf(0.5f*ph);
                    float t2 = (r & m) ? sp : -sp;
                    float nr = cp*ar - t2*ai;
                    float ni = cp*ai + t2*ar;
                    ar = nr; ai = ni;
                }
            }
#pragma unroll
            for (int e = 0; e < 4; ++e) {            // CNOT ring
                const int mc = 1 << (3 - e);
                const int mt = 1 << (3 - ((e + 1) & 3));
                float obr = __shfl_xor(ar, mt, 64);
                float obi = __shfl_xor(ai, mt, 64);
                if (r & mc) { ar = obr; ai = obi; }
            }
        }
        sU[r][c] = make_float2(ar, ai);
    }
    __syncthreads();

    {   // ---- Stage B: ReM[q][i][j] = sum_k z_q(k) Re(conj(U[k][i]) U[k][j])
        const int i = tid >> 4, j = tid & 15;
        float s0 = 0.f, s1 = 0.f, s2 = 0.f, s3 = 0.f;
#pragma unroll
        for (int k = 0; k < 16; ++k) {
            float2 uik = sU[k][i], ujk = sU[k][j];
            float pr = uik.x*ujk.x + uik.y*ujk.y;
            s0 += (k & 8) ? -pr : pr;
            s1 += (k & 4) ? -pr : pr;
            s2 += (k & 2) ? -pr : pr;
            s3 += (k & 1) ? -pr : pr;
        }
        sReM[0][i][j] = s0; sReM[1][i][j] = s1;
        sReM[2][i][j] = s2; sReM[3][i][j] = s3;
    }
    __syncthreads();

    // ---- Stage C: Ct[k81].q = tr(M_q P_{k81})/16, digits: 0=I 1=Z 2=X
    for (int idx = tid; idx < 324; idx += 256) {
        int q = idx / 81, k81 = idx % 81;
        int p0 = k81/27, p1 = (k81/9)%3, p2 = (k81/3)%3, p3 = k81%3;
        int xm = 0, zm = 0;
        if (p0 == 1) zm |= 8; else if (p0 == 2) xm |= 8;
        if (p1 == 1) zm |= 4; else if (p1 == 2) xm |= 4;
        if (p2 == 1) zm |= 2; else if (p2 == 2) xm |= 2;
        if (p3 == 1) zm |= 1; else if (p3 == 2) xm |= 1;
        float sum = 0.f;
#pragma unroll
        for (int j = 0; j < 16; ++j) {
            float sgn = (__popc(j & zm) & 1) ? -1.f : 1.f;
            sum += sgn * sReM[q][j ^ xm][j];
        }
        ((float*)Ct)[k81*4 + q] = sum * 0.0625f;
    }
}

// One (a,b) term: 4 fmas, all indices literal, all operands named scalars.
#define FB(a,b,G) { f4 c = C[(a)*9+(b)]; \
    A0 = fmaf(c[0], (G)*ga, A0); \
    A1 = fmaf(c[1], (G)*ga, A1); \
    A2 = fmaf(c[2], (G)*ga, A2); \
    A3 = fmaf(c[3], (G)*ga, A3); }

// One a-group: inner 9 b-terms accumulate t*, then fold with g01_a.
#define TA(a, GA) { float t0=0.f, t1=0.f, t2=0.f, t3=0.f; \
    { f4 c = C[(a)*9+0]; t0=fmaf(c[0],g23_0,t0); t1=fmaf(c[1],g23_0,t1); t2=fmaf(c[2],g23_0,t2); t3=fmaf(c[3],g23_0,t3); } \
    { f4 c = C[(a)*9+1]; t0=fmaf(c[0],g23_1,t0); t1=fmaf(c[1],g23_1,t1); t2=fmaf(c[2],g23_1,t2); t3=fmaf(c[3],g23_1,t3); } \
    { f4 c = C[(a)*9+2]; t0=fmaf(c[0],g23_2,t0); t1=fmaf(c[1],g23_2,t1); t2=fmaf(c[2],g23_2,t2); t3=fmaf(c[3],g23_2,t3); } \
    { f4 c = C[(a)*9+3]; t0=fmaf(c[0],g23_3,t0); t1=fmaf(c[1],g23_3,t1); t2=fmaf(c[2],g23_3,t2); t3=fmaf(c[3],g23_3,t3); } \
    { f4 c = C[(a)*9+4]; t0=fmaf(c[0],g23_4,t0); t1=fmaf(c[1],g23_4,t1); t2=fmaf(c[2],g23_4,t2); t3=fmaf(c[3],g23_4,t3); } \
    { f4 c = C[(a)*9+5]; t0=fmaf(c[0],g23_5,t0); t1=fmaf(c[1],g23_5,t1); t2=fmaf(c[2],g23_5,t2); t3=fmaf(c[3],g23_5,t3); } \
    { f4 c = C[(a)*9+6]; t0=fmaf(c[0],g23_6,t0); t1=fmaf(c[1],g23_6,t1); t2=fmaf(c[2],g23_6,t2); t3=fmaf(c[3],g23_6,t3); } \
    { f4 c = C[(a)*9+7]; t0=fmaf(c[0],g23_7,t0); t1=fmaf(c[1],g23_7,t1); t2=fmaf(c[2],g23_7,t2); t3=fmaf(c[3],g23_7,t3); } \
    { f4 c = C[(a)*9+8]; t0=fmaf(c[0],g23_8,t0); t1=fmaf(c[1],g23_8,t1); t2=fmaf(c[2],g23_8,t2); t3=fmaf(c[3],g23_8,t3); } \
    A0 = fmaf(t0, (GA), A0); A1 = fmaf(t1, (GA), A1); \
    A2 = fmaf(t2, (GA), A2); A3 = fmaf(t3, (GA), A3); }

__global__ __launch_bounds__(256) void fq_main(const float4* __restrict__ x,
                                               const float* __restrict__ Ct,
                                               float4* __restrict__ out) {
    const int i = blockIdx.x * 256 + threadIdx.x;
    c4ptr C = (c4ptr)(unsigned long long)Ct;   // uniform addr -> s_load_dwordx4

    float4 xv = x[i];
    float c0 = __cosf(xv.x), s0 = __sinf(xv.x);
    float c1 = __cosf(xv.y), s1 = __sinf(xv.y);
    float c2 = __cosf(xv.z), s2 = __sinf(xv.z);
    float c3 = __cosf(xv.w), s3 = __sinf(xv.w);

    // 18 NAMED products (no arrays anywhere -> nothing can be scratch-homed).
    // g01[p0*3+p1] = f0[p0]*f1[p1], f = {1, cos, sin}; same for g23.
    const float g01_0 = 1.f;
    const float g01_1 = c1,      g01_2 = s1;
    const float g01_3 = c0,      g01_6 = s0;
    const float g01_4 = c0 * c1, g01_5 = c0 * s1;
    const float g01_7 = s0 * c1, g01_8 = s0 * s1;
    const float g23_0 = 1.f;
    const float g23_1 = c3,      g23_2 = s3;
    const float g23_3 = c2,      g23_6 = s2;
    const float g23_4 = c2 * c3, g23_5 = c2 * s3;
    const float g23_7 = s2 * c3, g23_8 = s2 * s3;

    float A0 = 0.f, A1 = 0.f, A2 = 0.f, A3 = 0.f;
    TA(0, g01_0)
    TA(1, g01_1)
    TA(2, g01_2)
    TA(3, g01_3)
    TA(4, g01_4)
    TA(5, g01_5)
    TA(6, g01_6)
    TA(7, g01_7)
    TA(8, g01_8)

    out[i] = make_float4(A0, A1, A2, A3);
}

extern "C" void kernel_launch(void* const* d_in, const int* in_sizes, int n_in,
                              void* d_out, int out_size, void* d_ws, size_t ws_size,
                              hipStream_t stream) {
    const float* x = (const float*)d_in[0];     // [B,4] f32
    const float* w = (const float*)d_in[1];     // [3,4,2] f32
    float4* Ct = (float4*)d_ws;                 // 81 float4 scratch

    fq_setup<<<1, 256, 0, stream>>>(w, Ct);

    const int B = in_sizes[0] / 4;              // 1048576
    fq_main<<<B / 256, 256, 0, stream>>>((const float4*)x, (const float*)Ct,
                                         (float4*)d_out);
}